// Round 2
// baseline (2305.785 us; speedup 1.0000x reference)
//
#include <hip/hip_runtime.h>
#include <hip/hip_bf16.h>

#define LNUM 4
#define ENUM 12
#define CH 256
#define MLP 128
#define HW 196
#define BNUM 128
#define ROWLEN 14

// ---------------------------------------------------------------------------
// Transpose stem (B, C, HW) -> x (B, HW, C)
__global__ __launch_bounds__(256) void transpose_stem(const float* __restrict__ stem,
                                                      float* __restrict__ x) {
  __shared__ float tile[32][33];
  int b = blockIdx.z;
  int c0 = blockIdx.x * 32;   // channel tile
  int p0 = blockIdx.y * 32;   // position tile
  int tx = threadIdx.x;       // 32
  int ty = threadIdx.y;       // 8
  for (int i = ty; i < 32; i += 8) {
    int c = c0 + i, p = p0 + tx;
    if (p < HW) tile[i][tx] = stem[(size_t)b * CH * HW + (size_t)c * HW + p];
  }
  __syncthreads();
  for (int i = ty; i < 32; i += 8) {
    int p = p0 + i, c = c0 + tx;
    if (p < HW) x[(size_t)b * HW * CH + (size_t)p * CH + c] = tile[tx][i];
  }
}

// ---------------------------------------------------------------------------
// Router: per-batch mean over HW, logits, softmax, argmax, weight
__global__ __launch_bounds__(256) void router_kernel(
    const float* __restrict__ x, const float* __restrict__ gate_w,
    const float* __restrict__ gate_b, float* __restrict__ probs_out,
    float* __restrict__ idx_out, float* __restrict__ weight,
    int* __restrict__ eidx, int li) {
  int b = blockIdx.x;
  int c = threadIdx.x;  // 256
  const float* xb = x + (size_t)b * HW * CH;
  float s = 0.f;
  for (int p = 0; p < HW; ++p) s += xb[(size_t)p * CH + c];
  __shared__ float r[CH];
  r[c] = s * (1.0f / (float)HW);
  __syncthreads();
  __shared__ float logits[ENUM];
  if (c < ENUM) {
    float acc = gate_b[li * ENUM + c];
    for (int k = 0; k < CH; ++k)
      acc += r[k] * gate_w[((size_t)li * CH + k) * ENUM + c];
    logits[c] = acc;
  }
  __syncthreads();
  if (c == 0) {
    float mx = logits[0]; int am = 0;
    for (int e = 1; e < ENUM; ++e) if (logits[e] > mx) { mx = logits[e]; am = e; }
    float pr[ENUM]; float den = 0.f;
    for (int e = 0; e < ENUM; ++e) { pr[e] = expf(logits[e] - mx); den += pr[e]; }
    float inv = 1.0f / den;
    for (int e = 0; e < ENUM; ++e) pr[e] *= inv;
    for (int e = 0; e < ENUM; ++e)
      probs_out[(size_t)(li * BNUM + b) * ENUM + e] = pr[e];
    idx_out[li * BNUM + b] = (float)am;
    float pmax = pr[am];
    weight[b] = pmax / (pmax + 1e-8f);
    eidx[b] = am;
  }
}

// ---------------------------------------------------------------------------
// LayerNorm over C=256, expert-specific gamma/beta. One token per block.
__global__ __launch_bounds__(256) void ln_kernel(
    const float* __restrict__ xin, float* __restrict__ hout,
    const float* __restrict__ g, const float* __restrict__ bta,
    const int* __restrict__ eidx, int li) {
  int t = blockIdx.x;          // b*196 + p
  int b = t / HW;
  int c = threadIdx.x;
  int e = eidx[b];
  float vx = xin[(size_t)t * CH + c];
  float s = vx;
  for (int off = 32; off > 0; off >>= 1) s += __shfl_down(s, off, 64);
  __shared__ float wsum[4];
  __shared__ float red[2];
  int wid = c >> 6, lane = c & 63;
  if (lane == 0) wsum[wid] = s;
  __syncthreads();
  if (c == 0) red[0] = (wsum[0] + wsum[1] + wsum[2] + wsum[3]) * (1.0f / (float)CH);
  __syncthreads();
  float mu = red[0];
  float d = vx - mu;
  float s2 = d * d;
  for (int off = 32; off > 0; off >>= 1) s2 += __shfl_down(s2, off, 64);
  if (lane == 0) wsum[wid] = s2;
  __syncthreads();
  if (c == 0) red[1] = (wsum[0] + wsum[1] + wsum[2] + wsum[3]) * (1.0f / (float)CH);
  __syncthreads();
  float rs = rsqrtf(red[1] + 1e-5f);
  size_t gb = ((size_t)li * ENUM + e) * CH + c;
  hout[(size_t)t * CH + c] = d * rs * g[gb] + bta[gb];
}

// ---------------------------------------------------------------------------
// Grouped GEMM: C[b] (M x N) = A[b] (M x K) @ W[li, e[b]] (K x N) + bias
// EPI: 0 = store, 1 = gelu+store, 2 = +residual in-place, 3 = +residual, scale, dual write
#define TILE 64
#define KT 16
template <int EPI>
__global__ __launch_bounds__(256) void gemm_kernel(
    const float* __restrict__ A, const float* __restrict__ Wt,
    const float* __restrict__ bias, float* __restrict__ Cres,
    float* __restrict__ Cout2, const int* __restrict__ eidx,
    const float* __restrict__ wgt, int Mdim, int Ndim, int Kdim, int li) {
  int b = blockIdx.z;
  int mt = blockIdx.y;
  int nt = blockIdx.x;
  int e = eidx[b];
  const float* Ab = A + (size_t)b * Mdim * Kdim;
  const float* Wb = Wt + ((size_t)li * ENUM + e) * Kdim * Ndim;
  const float* bb = bias + ((size_t)li * ENUM + e) * Ndim;

  __shared__ float As[KT][TILE + 1];
  __shared__ float Bs[KT][TILE + 1];

  int tid = threadIdx.x;
  int tx = tid % 16, ty = tid / 16;
  int m0 = mt * TILE, n0 = nt * TILE;

  float acc[4][4] = {};
  for (int k0 = 0; k0 < Kdim; k0 += KT) {
    {
      int kq = tid % KT;
      int mrow = tid / KT;
      for (int i = 0; i < 4; ++i) {
        int mm = m0 + mrow + i * 16;
        As[kq][mrow + i * 16] = (mm < Mdim) ? Ab[(size_t)mm * Kdim + k0 + kq] : 0.f;
      }
    }
    {
      int n = tid % 64;
      int kr = tid / 64;
      for (int i = 0; i < 4; ++i) {
        int kk = kr + i * 4;
        Bs[kk][n] = Wb[(size_t)(k0 + kk) * Ndim + n0 + n];
      }
    }
    __syncthreads();
#pragma unroll
    for (int kk = 0; kk < KT; ++kk) {
      float a[4], bv[4];
#pragma unroll
      for (int i = 0; i < 4; ++i) a[i] = As[kk][ty * 4 + i];
#pragma unroll
      for (int j = 0; j < 4; ++j) bv[j] = Bs[kk][tx * 4 + j];
#pragma unroll
      for (int i = 0; i < 4; ++i)
#pragma unroll
        for (int j = 0; j < 4; ++j) acc[i][j] = fmaf(a[i], bv[j], acc[i][j]);
    }
    __syncthreads();
  }
  float w = (EPI == 3) ? wgt[b] : 1.0f;
  for (int i = 0; i < 4; ++i) {
    int mm = m0 + ty * 4 + i;
    if (mm >= Mdim) continue;
    for (int j = 0; j < 4; ++j) {
      int n = n0 + tx * 4 + j;
      float vsum = acc[i][j] + bb[n];
      if (EPI == 1) vsum = 0.5f * vsum * (1.0f + erff(vsum * 0.70710678118654752f));
      size_t off = ((size_t)b * Mdim + mm) * Ndim + n;
      if (EPI == 2) {
        vsum += Cres[off];
        Cres[off] = vsum;
      } else if (EPI == 3) {
        vsum = (vsum + Cres[off]) * w;
        Cres[off] = vsum;
        Cout2[off] = vsum;
      } else {
        Cres[off] = vsum;
      }
    }
  }
}

// ---------------------------------------------------------------------------
// Row-local attention: per (batch, row). q,k,v: (B, HW, C) with c = head*64+d
__global__ __launch_bounds__(256) void attn_kernel(
    const float* __restrict__ q, const float* __restrict__ k,
    const float* __restrict__ v, float* __restrict__ o) {
  int br = blockIdx.x;  // b*14 + row
  int b = br / ROWLEN, row = br % ROWLEN;
  size_t base = ((size_t)b * HW + (size_t)row * ROWLEN) * CH;
  __shared__ float qs[ROWLEN][CH + 1];
  __shared__ float ks[ROWLEN][CH + 1];
  __shared__ float vs[ROWLEN][CH + 1];
  __shared__ float sc[4][ROWLEN][ROWLEN];
  int tid = threadIdx.x;  // 256
  for (int w = 0; w < ROWLEN; ++w) {
    qs[w][tid] = q[base + (size_t)w * CH + tid];
    ks[w][tid] = k[base + (size_t)w * CH + tid];
    vs[w][tid] = v[base + (size_t)w * CH + tid];
  }
  __syncthreads();
  for (int sidx = tid; sidx < 4 * ROWLEN * ROWLEN; sidx += 256) {
    int n = sidx / (ROWLEN * ROWLEN);
    int rem = sidx % (ROWLEN * ROWLEN);
    int i = rem / ROWLEN, j = rem % ROWLEN;
    const float* qp = &qs[i][n * 64];
    const float* kp = &ks[j][n * 64];
    float s = 0.f;
#pragma unroll
    for (int d = 0; d < 64; ++d) s = fmaf(qp[d], kp[d], s);
    sc[n][i][j] = s * 0.125f;
  }
  __syncthreads();
  if (tid < 4 * ROWLEN) {
    int n = tid / ROWLEN, i = tid % ROWLEN;
    float mx = sc[n][i][0];
    for (int j = 1; j < ROWLEN; ++j) mx = fmaxf(mx, sc[n][i][j]);
    float ex[ROWLEN]; float den = 0.f;
    for (int j = 0; j < ROWLEN; ++j) { ex[j] = expf(sc[n][i][j] - mx); den += ex[j]; }
    float inv = 1.0f / den;
    for (int j = 0; j < ROWLEN; ++j) sc[n][i][j] = ex[j] * inv;
  }
  __syncthreads();
  int n = tid / 64;
  for (int i = 0; i < ROWLEN; ++i) {
    float s = 0.f;
#pragma unroll
    for (int j = 0; j < ROWLEN; ++j) s = fmaf(sc[n][i][j], vs[j][tid], s);
    o[base + (size_t)i * CH + tid] = s;
  }
}

// ---------------------------------------------------------------------------
extern "C" void kernel_launch(void* const* d_in, const int* in_sizes, int n_in,
                              void* d_out, int out_size, void* d_ws, size_t ws_size,
                              hipStream_t stream) {
  const float* stem = (const float*)d_in[0];
  const float* gate_w = (const float*)d_in[1];
  const float* gate_b = (const float*)d_in[2];
  const float* ln1_g = (const float*)d_in[3];
  const float* ln1_b = (const float*)d_in[4];
  const float* wq = (const float*)d_in[5];
  const float* bq = (const float*)d_in[6];
  const float* wk = (const float*)d_in[7];
  const float* bk = (const float*)d_in[8];
  const float* wv = (const float*)d_in[9];
  const float* bv = (const float*)d_in[10];
  const float* wo = (const float*)d_in[11];
  const float* bo = (const float*)d_in[12];
  const float* ln2_g = (const float*)d_in[13];
  const float* ln2_b = (const float*)d_in[14];
  const float* w1 = (const float*)d_in[15];
  const float* b1 = (const float*)d_in[16];
  const float* w2 = (const float*)d_in[17];
  const float* b2 = (const float*)d_in[18];

  float* out = (float*)d_out;
  float* ws = (float*)d_ws;
  const size_t IMG = (size_t)BNUM * HW * CH;       // 6,422,528
  float* x = ws;
  float* h = ws + IMG;
  float* q = ws + 2 * IMG;
  float* k = ws + 3 * IMG;
  float* v = ws + 4 * IMG;
  float* m = q;  // alias: q/k/v dead after attn; m (B*HW*MLP) fits in q's slot
  float* weight = ws + 5 * IMG;
  int* eidx = (int*)(weight + BNUM);

  float* probs_out = out + 4 * IMG;
  float* idx_out = probs_out + (size_t)LNUM * BNUM * ENUM;

  // stem (B,C,H,W) -> x (B,HW,C)
  transpose_stem<<<dim3(8, 7, BNUM), dim3(32, 8), 0, stream>>>(stem, x);

  for (int li = 0; li < LNUM; ++li) {
    router_kernel<<<BNUM, 256, 0, stream>>>(x, gate_w, gate_b, probs_out, idx_out,
                                            weight, eidx, li);
    ln_kernel<<<BNUM * HW, 256, 0, stream>>>(x, h, ln1_g, ln1_b, eidx, li);
    gemm_kernel<0><<<dim3(4, 4, BNUM), 256, 0, stream>>>(h, wq, bq, q, nullptr,
                                                         eidx, nullptr, HW, CH, CH, li);
    gemm_kernel<0><<<dim3(4, 4, BNUM), 256, 0, stream>>>(h, wk, bk, k, nullptr,
                                                         eidx, nullptr, HW, CH, CH, li);
    gemm_kernel<0><<<dim3(4, 4, BNUM), 256, 0, stream>>>(h, wv, bv, v, nullptr,
                                                         eidx, nullptr, HW, CH, CH, li);
    attn_kernel<<<BNUM * ROWLEN, 256, 0, stream>>>(q, k, v, h);  // o -> h
    gemm_kernel<2><<<dim3(4, 4, BNUM), 256, 0, stream>>>(h, wo, bo, x, nullptr,
                                                         eidx, nullptr, HW, CH, CH, li);
    ln_kernel<<<BNUM * HW, 256, 0, stream>>>(x, h, ln2_g, ln2_b, eidx, li);
    gemm_kernel<1><<<dim3(2, 4, BNUM), 256, 0, stream>>>(h, w1, b1, m, nullptr,
                                                         eidx, nullptr, HW, MLP, CH, li);
    gemm_kernel<3><<<dim3(4, 4, BNUM), 256, 0, stream>>>(m, w2, b2, x, out + (size_t)li * IMG,
                                                         eidx, weight, HW, CH, MLP, li);
  }
}

// Round 4
// 1541.190 us; speedup vs baseline: 1.4961x; 1.4961x over previous
//
#include <hip/hip_runtime.h>
#include <hip/hip_bf16.h>

#define LNUM 4
#define ENUM 12
#define CH 256
#define MLP 128
#define HW 196
#define BNUM 128
#define ROWLEN 14
#define MTOT (BNUM * HW)   // 25088 rows
#define BM 128
#define BN 128
#define BK 16
#define MAXTILE 208        // ceil(25088/128)=196 + up to 12 partial tiles

// ---------------------------------------------------------------------------
// Transpose stem (B, C, HW) -> x (B, HW, C)
__global__ __launch_bounds__(256) void transpose_stem(const float* __restrict__ stem,
                                                      float* __restrict__ x) {
  __shared__ float tile[32][33];
  int b = blockIdx.z;
  int c0 = blockIdx.x * 32;
  int p0 = blockIdx.y * 32;
  int tx = threadIdx.x;
  int ty = threadIdx.y;
  for (int i = ty; i < 32; i += 8) {
    int c = c0 + i, p = p0 + tx;
    if (p < HW) tile[i][tx] = stem[(size_t)b * CH * HW + (size_t)c * HW + p];
  }
  __syncthreads();
  for (int i = ty; i < 32; i += 8) {
    int p = p0 + i, c = c0 + tx;
    if (p < HW) x[(size_t)b * HW * CH + (size_t)p * CH + c] = tile[tx][i];
  }
}

// ---------------------------------------------------------------------------
// Router: per-batch mean over HW, logits, softmax, argmax, weight
__global__ __launch_bounds__(256) void router_kernel(
    const float* __restrict__ x, const float* __restrict__ gate_w,
    const float* __restrict__ gate_b, float* __restrict__ probs_out,
    float* __restrict__ idx_out, float* __restrict__ weight,
    int* __restrict__ eidx, int li) {
  int b = blockIdx.x;
  int c = threadIdx.x;  // 256
  const float* xb = x + (size_t)b * HW * CH;
  float s = 0.f;
  for (int p = 0; p < HW; ++p) s += xb[(size_t)p * CH + c];
  __shared__ float r[CH];
  r[c] = s * (1.0f / (float)HW);
  __syncthreads();
  __shared__ float logits[ENUM];
  if (c < ENUM) {
    float acc = gate_b[li * ENUM + c];
    for (int k = 0; k < CH; ++k)
      acc += r[k] * gate_w[((size_t)li * CH + k) * ENUM + c];
    logits[c] = acc;
  }
  __syncthreads();
  if (c == 0) {
    float mx = logits[0]; int am = 0;
    for (int e = 1; e < ENUM; ++e) if (logits[e] > mx) { mx = logits[e]; am = e; }
    float pr[ENUM]; float den = 0.f;
    for (int e = 0; e < ENUM; ++e) { pr[e] = expf(logits[e] - mx); den += pr[e]; }
    float inv = 1.0f / den;
    for (int e = 0; e < ENUM; ++e) pr[e] *= inv;
    for (int e = 0; e < ENUM; ++e)
      probs_out[(size_t)(li * BNUM + b) * ENUM + e] = pr[e];
    idx_out[li * BNUM + b] = (float)am;
    float pmax = pr[am];
    weight[b] = pmax / (pmax + 1e-8f);
    eidx[b] = am;
  }
}

// ---------------------------------------------------------------------------
// Build batch permutation sorted by expert + GEMM tile table.
__global__ void route_plan(const int* __restrict__ eidx, int* __restrict__ perm,
                           int* __restrict__ tile_e, int* __restrict__ tile_row0,
                           int* __restrict__ tile_rows) {
  __shared__ int cnt[ENUM], start[ENUM];
  int t = threadIdx.x;  // 64
  if (t < ENUM) {
    int c = 0;
    for (int b = 0; b < BNUM; ++b) if (eidx[b] == t) ++c;
    cnt[t] = c;
  }
  __syncthreads();
  if (t == 0) {
    int s = 0;
    for (int e = 0; e < ENUM; ++e) { start[e] = s; s += cnt[e]; }
  }
  __syncthreads();
  if (t < ENUM) {
    int pos = start[t];
    for (int b = 0; b < BNUM; ++b) if (eidx[b] == t) perm[pos++] = b;
  }
  __syncthreads();
  if (t == 0) {
    int tile = 0;
    for (int e = 0; e < ENUM; ++e) {
      int rows = cnt[e] * HW;
      int row0 = start[e] * HW;
      int off = 0;
      while (off < rows) {
        tile_e[tile] = e;
        tile_row0[tile] = row0 + off;
        int rem = rows - off;
        tile_rows[tile] = rem < BM ? rem : BM;
        ++tile; off += BM;
      }
    }
    for (; tile < MAXTILE; ++tile) { tile_rows[tile] = 0; tile_e[tile] = 0; tile_row0[tile] = 0; }
  }
}

// ---------------------------------------------------------------------------
// LayerNorm: reads unsorted x via perm, writes sorted h.
__global__ __launch_bounds__(256) void ln_kernel(
    const float* __restrict__ xin, float* __restrict__ hout,
    const float* __restrict__ g, const float* __restrict__ bta,
    const int* __restrict__ eidx, const int* __restrict__ perm, int li) {
  int t = blockIdx.x;          // sorted token id
  int s = t / HW, p = t - s * HW;
  int b = perm[s];
  int e = eidx[b];
  int c = threadIdx.x;
  float vx = xin[((size_t)b * HW + p) * CH + c];
  float sm = vx;
  for (int off = 32; off > 0; off >>= 1) sm += __shfl_down(sm, off, 64);
  __shared__ float wsum[4];
  __shared__ float red[2];
  int wid = c >> 6, lane = c & 63;
  if (lane == 0) wsum[wid] = sm;
  __syncthreads();
  if (c == 0) red[0] = (wsum[0] + wsum[1] + wsum[2] + wsum[3]) * (1.0f / (float)CH);
  __syncthreads();
  float mu = red[0];
  float d = vx - mu;
  float s2 = d * d;
  for (int off = 32; off > 0; off >>= 1) s2 += __shfl_down(s2, off, 64);
  if (lane == 0) wsum[wid] = s2;
  __syncthreads();
  if (c == 0) red[1] = (wsum[0] + wsum[1] + wsum[2] + wsum[3]) * (1.0f / (float)CH);
  __syncthreads();
  float rs = rsqrtf(red[1] + 1e-5f);
  size_t gb = ((size_t)li * ENUM + e) * CH + c;
  hout[(size_t)t * CH + c] = d * rs * g[gb] + bta[gb];
}

// ---------------------------------------------------------------------------
// Expert-sorted grouped GEMM. Block tile BM x BN, K-step BK. 256 thr, 8x8/thr.
// EPI: 0 = QKV (3 weights via nt>>1, plain store)
//      1 = GELU store (W1)
//      2 = residual add into unsorted X (WO)
//      3 = residual + scale + dual write (W2)
template <int EPI>
__global__ __launch_bounds__(256) void gemm_kernel(
    const float* __restrict__ A,
    const float* __restrict__ Wa, const float* __restrict__ Wb_, const float* __restrict__ Wc,
    const float* __restrict__ Ba, const float* __restrict__ Bb_, const float* __restrict__ Bc,
    float* __restrict__ Oa, float* __restrict__ Ob, float* __restrict__ Oc,
    float* __restrict__ X, const float* __restrict__ wgt,
    const int* __restrict__ tile_e, const int* __restrict__ tile_row0,
    const int* __restrict__ tile_rows, const int* __restrict__ perm,
    int Ndim, int Kdim, int li) {
  int tileid = blockIdx.y;
  int rows = tile_rows[tileid];
  if (rows <= 0) return;
  int row0 = tile_row0[tileid];
  int e = tile_e[tileid];
  int nt = blockIdx.x;

  int wsel = (EPI == 0) ? (nt >> 1) : 0;
  int ncol0 = (EPI == 0) ? ((nt & 1) * BN) : (nt * BN);
  const float* Wsel = (EPI == 0) ? (wsel == 0 ? Wa : (wsel == 1 ? Wb_ : Wc)) : Wa;
  const float* Bsel = (EPI == 0) ? (wsel == 0 ? Ba : (wsel == 1 ? Bb_ : Bc)) : Ba;
  float* Osel = (EPI == 0) ? (wsel == 0 ? Oa : (wsel == 1 ? Ob : Oc)) : Oa;

  const float* Wb = Wsel + ((size_t)li * ENUM + e) * Kdim * Ndim;
  const float* bb = Bsel + ((size_t)li * ENUM + e) * Ndim;

  __shared__ __align__(16) float As[BK][BM + 4];
  __shared__ __align__(16) float Bs[BK][BN + 4];

  int tid = threadIdx.x;
  int tx = tid & 15, ty = tid >> 4;

  // staging maps
  int tA_row = tid >> 2;            // 0..63
  int tA_k = (tid & 3) * 4;         // 0,4,8,12
  int tB_row = tid >> 4;            // 0..15
  int tB_n = (tid & 15) * 8;        // 0..120

  float acc[8][8];
#pragma unroll
  for (int i = 0; i < 8; ++i)
#pragma unroll
    for (int j = 0; j < 8; ++j) acc[i][j] = 0.f;

  int ra = tA_row < rows ? row0 + tA_row : row0;
  int rb = (tA_row + 64) < rows ? row0 + tA_row + 64 : row0;

  for (int k0 = 0; k0 < Kdim; k0 += BK) {
    float4 va0 = *reinterpret_cast<const float4*>(&A[(size_t)ra * Kdim + k0 + tA_k]);
    float4 va1 = *reinterpret_cast<const float4*>(&A[(size_t)rb * Kdim + k0 + tA_k]);
    const float* Wrow = Wb + (size_t)(k0 + tB_row) * Ndim + ncol0 + tB_n;
    float4 vb0 = *reinterpret_cast<const float4*>(Wrow);
    float4 vb1 = *reinterpret_cast<const float4*>(Wrow + 4);
    As[tA_k + 0][tA_row] = va0.x;
    As[tA_k + 1][tA_row] = va0.y;
    As[tA_k + 2][tA_row] = va0.z;
    As[tA_k + 3][tA_row] = va0.w;
    As[tA_k + 0][tA_row + 64] = va1.x;
    As[tA_k + 1][tA_row + 64] = va1.y;
    As[tA_k + 2][tA_row + 64] = va1.z;
    As[tA_k + 3][tA_row + 64] = va1.w;
    *reinterpret_cast<float4*>(&Bs[tB_row][tB_n]) = vb0;
    *reinterpret_cast<float4*>(&Bs[tB_row][tB_n + 4]) = vb1;
    __syncthreads();
#pragma unroll
    for (int kk = 0; kk < BK; ++kk) {
      float4 a0 = *reinterpret_cast<const float4*>(&As[kk][ty * 4]);
      float4 a1 = *reinterpret_cast<const float4*>(&As[kk][64 + ty * 4]);
      float4 b0 = *reinterpret_cast<const float4*>(&Bs[kk][tx * 4]);
      float4 b1 = *reinterpret_cast<const float4*>(&Bs[kk][64 + tx * 4]);
      float am[8] = {a0.x, a0.y, a0.z, a0.w, a1.x, a1.y, a1.z, a1.w};
      float bn[8] = {b0.x, b0.y, b0.z, b0.w, b1.x, b1.y, b1.z, b1.w};
#pragma unroll
      for (int i = 0; i < 8; ++i)
#pragma unroll
        for (int j = 0; j < 8; ++j) acc[i][j] = fmaf(am[i], bn[j], acc[i][j]);
    }
    __syncthreads();
  }

  // column indices within output matrix
  int cn[8];
#pragma unroll
  for (int j = 0; j < 8; ++j)
    cn[j] = ncol0 + (j < 4 ? tx * 4 + j : 64 + tx * 4 + (j - 4));
  float bv[8];
#pragma unroll
  for (int j = 0; j < 8; ++j) bv[j] = bb[cn[j]];

#pragma unroll
  for (int i = 0; i < 8; ++i) {
    int row_l = (i < 4) ? (ty * 4 + i) : (64 + ty * 4 + (i - 4));
    if (row_l >= rows) continue;
    int r = row0 + row_l;
    if (EPI == 0) {
#pragma unroll
      for (int j = 0; j < 8; ++j)
        Osel[(size_t)r * CH + cn[j]] = acc[i][j] + bv[j];
    } else if (EPI == 1) {
#pragma unroll
      for (int j = 0; j < 8; ++j) {
        float v = acc[i][j] + bv[j];
        Oa[(size_t)r * MLP + cn[j]] = 0.5f * v * (1.0f + erff(v * 0.70710678118654752f));
      }
    } else {
      int s = r / HW, p = r - s * HW;
      int b = perm[s];
      size_t g = ((size_t)b * HW + p) * CH;
      if (EPI == 2) {
#pragma unroll
        for (int j = 0; j < 8; ++j)
          X[g + cn[j]] += acc[i][j] + bv[j];
      } else {
        float w = wgt[b];
#pragma unroll
        for (int j = 0; j < 8; ++j) {
          float v = (acc[i][j] + bv[j] + X[g + cn[j]]) * w;
          X[g + cn[j]] = v;
          Ob[g + cn[j]] = v;
        }
      }
    }
  }
}

// ---------------------------------------------------------------------------
// Row-local attention on sorted buffers.
__global__ __launch_bounds__(256) void attn_kernel(
    const float* __restrict__ q, const float* __restrict__ k,
    const float* __restrict__ v, float* __restrict__ o) {
  int br = blockIdx.x;  // sorted_batch*14 + row
  int b = br / ROWLEN, row = br % ROWLEN;
  size_t base = ((size_t)b * HW + (size_t)row * ROWLEN) * CH;
  __shared__ float qs[ROWLEN][CH + 1];
  __shared__ float ks[ROWLEN][CH + 1];
  __shared__ float vs[ROWLEN][CH + 1];
  __shared__ float sc[4][ROWLEN][ROWLEN];
  int tid = threadIdx.x;  // 256
  for (int w = 0; w < ROWLEN; ++w) {
    qs[w][tid] = q[base + (size_t)w * CH + tid];
    ks[w][tid] = k[base + (size_t)w * CH + tid];
    vs[w][tid] = v[base + (size_t)w * CH + tid];
  }
  __syncthreads();
  for (int sidx = tid; sidx < 4 * ROWLEN * ROWLEN; sidx += 256) {
    int n = sidx / (ROWLEN * ROWLEN);
    int rem = sidx % (ROWLEN * ROWLEN);
    int i = rem / ROWLEN, j = rem % ROWLEN;
    const float* qp = &qs[i][n * 64];
    const float* kp = &ks[j][n * 64];
    float s = 0.f;
#pragma unroll
    for (int d = 0; d < 64; ++d) s = fmaf(qp[d], kp[d], s);
    sc[n][i][j] = s * 0.125f;
  }
  __syncthreads();
  if (tid < 4 * ROWLEN) {
    int n = tid / ROWLEN, i = tid % ROWLEN;
    float mx = sc[n][i][0];
    for (int j = 1; j < ROWLEN; ++j) mx = fmaxf(mx, sc[n][i][j]);
    float ex[ROWLEN]; float den = 0.f;
    for (int j = 0; j < ROWLEN; ++j) { ex[j] = expf(sc[n][i][j] - mx); den += ex[j]; }
    float inv = 1.0f / den;
    for (int j = 0; j < ROWLEN; ++j) sc[n][i][j] = ex[j] * inv;
  }
  __syncthreads();
  int n = tid / 64;
  for (int i = 0; i < ROWLEN; ++i) {
    float s = 0.f;
#pragma unroll
    for (int j = 0; j < ROWLEN; ++j) s = fmaf(sc[n][i][j], vs[j][tid], s);
    o[base + (size_t)i * CH + tid] = s;
  }
}

// ---------------------------------------------------------------------------
extern "C" void kernel_launch(void* const* d_in, const int* in_sizes, int n_in,
                              void* d_out, int out_size, void* d_ws, size_t ws_size,
                              hipStream_t stream) {
  const float* stem = (const float*)d_in[0];
  const float* gate_w = (const float*)d_in[1];
  const float* gate_b = (const float*)d_in[2];
  const float* ln1_g = (const float*)d_in[3];
  const float* ln1_b = (const float*)d_in[4];
  const float* wq = (const float*)d_in[5];
  const float* bq = (const float*)d_in[6];
  const float* wk = (const float*)d_in[7];
  const float* bk = (const float*)d_in[8];
  const float* wv = (const float*)d_in[9];
  const float* bv = (const float*)d_in[10];
  const float* wo = (const float*)d_in[11];
  const float* bo = (const float*)d_in[12];
  const float* ln2_g = (const float*)d_in[13];
  const float* ln2_b = (const float*)d_in[14];
  const float* w1 = (const float*)d_in[15];
  const float* b1 = (const float*)d_in[16];
  const float* w2 = (const float*)d_in[17];
  const float* b2 = (const float*)d_in[18];

  float* out = (float*)d_out;
  float* ws = (float*)d_ws;
  const size_t IMG = (size_t)BNUM * HW * CH;  // 6,422,528 floats
  float* x = ws;
  float* h = ws + IMG;
  float* q = ws + 2 * IMG;
  float* k = ws + 3 * IMG;
  float* v = ws + 4 * IMG;
  float* m = q;  // alias: q/k/v dead after attn; m is MTOT x MLP (half of IMG)
  float* weight = ws + 5 * IMG;
  int* eidx = (int*)(weight + BNUM);
  int* perm = eidx + BNUM;
  int* tile_e = perm + BNUM;
  int* tile_row0 = tile_e + MAXTILE;
  int* tile_rows = tile_row0 + MAXTILE;

  float* probs_out = out + 4 * IMG;
  float* idx_out = probs_out + (size_t)LNUM * BNUM * ENUM;

  transpose_stem<<<dim3(8, 7, BNUM), dim3(32, 8), 0, stream>>>(stem, x);

  for (int li = 0; li < LNUM; ++li) {
    router_kernel<<<BNUM, 256, 0, stream>>>(x, gate_w, gate_b, probs_out, idx_out,
                                            weight, eidx, li);
    route_plan<<<1, 64, 0, stream>>>(eidx, perm, tile_e, tile_row0, tile_rows);
    ln_kernel<<<MTOT, 256, 0, stream>>>(x, h, ln1_g, ln1_b, eidx, perm, li);
    gemm_kernel<0><<<dim3(6, MAXTILE), 256, 0, stream>>>(
        h, wq, wk, wv, bq, bk, bv, q, k, v, nullptr, nullptr,
        tile_e, tile_row0, tile_rows, perm, CH, CH, li);
    attn_kernel<<<BNUM * ROWLEN, 256, 0, stream>>>(q, k, v, h);
    gemm_kernel<2><<<dim3(2, MAXTILE), 256, 0, stream>>>(
        h, wo, nullptr, nullptr, bo, nullptr, nullptr, nullptr, nullptr, nullptr,
        x, nullptr, tile_e, tile_row0, tile_rows, perm, CH, CH, li);
    ln_kernel<<<MTOT, 256, 0, stream>>>(x, h, ln2_g, ln2_b, eidx, perm, li);
    gemm_kernel<1><<<dim3(1, MAXTILE), 256, 0, stream>>>(
        h, w1, nullptr, nullptr, b1, nullptr, nullptr, m, nullptr, nullptr,
        nullptr, nullptr, tile_e, tile_row0, tile_rows, perm, MLP, CH, li);
    gemm_kernel<3><<<dim3(2, MAXTILE), 256, 0, stream>>>(
        m, w2, nullptr, nullptr, b2, nullptr, nullptr, nullptr, out + (size_t)li * IMG,
        nullptr, x, weight, tile_e, tile_row0, tile_rows, perm, CH, MLP, li);
  }
}

// Round 5
// 1112.671 us; speedup vs baseline: 2.0723x; 1.3851x over previous
//
#include <hip/hip_runtime.h>
#include <hip/hip_bf16.h>

#define LNUM 4
#define ENUM 12
#define CH 256
#define MLP 128
#define HW 196
#define BNUM 128
#define ROWLEN 14
#define MTOT (BNUM * HW)   // 25088 rows
#define BM 128
#define MAXTILE 208        // ceil(25088/128)=196 + up to 12 partial tiles

using bf16x8 = __attribute__((ext_vector_type(8))) short;
using f32x4 = __attribute__((ext_vector_type(4))) float;

__device__ inline unsigned short f2bf(float v) {
  __hip_bfloat16 b = __float2bfloat16(v);   // RNE
  return *reinterpret_cast<unsigned short*>(&b);
}
__device__ inline float bf2f(unsigned short u) {
  union { unsigned int i; float f; } cv;
  cv.i = ((unsigned int)u) << 16;
  return cv.f;
}
__device__ inline void split_bf(float v, unsigned short& hi, unsigned short& lo) {
  hi = f2bf(v);
  lo = f2bf(v - bf2f(hi));
}

// ---------------------------------------------------------------------------
// Transpose stem (B, C, HW) -> x (B, HW, C)
__global__ __launch_bounds__(256) void transpose_stem(const float* __restrict__ stem,
                                                      float* __restrict__ x) {
  __shared__ float tile[32][33];
  int b = blockIdx.z;
  int c0 = blockIdx.x * 32;
  int p0 = blockIdx.y * 32;
  int tx = threadIdx.x;
  int ty = threadIdx.y;
  for (int i = ty; i < 32; i += 8) {
    int c = c0 + i, p = p0 + tx;
    if (p < HW) tile[i][tx] = stem[(size_t)b * CH * HW + (size_t)c * HW + p];
  }
  __syncthreads();
  for (int i = ty; i < 32; i += 8) {
    int p = p0 + i, c = c0 + tx;
    if (p < HW) x[(size_t)b * HW * CH + (size_t)p * CH + c] = tile[tx][i];
  }
}

// ---------------------------------------------------------------------------
// Router: per-batch mean over HW, logits, softmax, argmax, weight
__global__ __launch_bounds__(256) void router_kernel(
    const float* __restrict__ x, const float* __restrict__ gate_w,
    const float* __restrict__ gate_b, float* __restrict__ probs_out,
    float* __restrict__ idx_out, float* __restrict__ weight,
    int* __restrict__ eidx, int li) {
  int b = blockIdx.x;
  int c = threadIdx.x;  // 256
  const float* xb = x + (size_t)b * HW * CH;
  float s = 0.f;
  for (int p = 0; p < HW; ++p) s += xb[(size_t)p * CH + c];
  __shared__ float r[CH];
  r[c] = s * (1.0f / (float)HW);
  __syncthreads();
  __shared__ float logits[ENUM];
  if (c < ENUM) {
    float acc = gate_b[li * ENUM + c];
    for (int k = 0; k < CH; ++k)
      acc += r[k] * gate_w[((size_t)li * CH + k) * ENUM + c];
    logits[c] = acc;
  }
  __syncthreads();
  if (c == 0) {
    float mx = logits[0]; int am = 0;
    for (int e = 1; e < ENUM; ++e) if (logits[e] > mx) { mx = logits[e]; am = e; }
    float pr[ENUM]; float den = 0.f;
    for (int e = 0; e < ENUM; ++e) { pr[e] = expf(logits[e] - mx); den += pr[e]; }
    float inv = 1.0f / den;
    for (int e = 0; e < ENUM; ++e) pr[e] *= inv;
    for (int e = 0; e < ENUM; ++e)
      probs_out[(size_t)(li * BNUM + b) * ENUM + e] = pr[e];
    idx_out[li * BNUM + b] = (float)am;
    float pmax = pr[am];
    weight[b] = pmax / (pmax + 1e-8f);
    eidx[b] = am;
  }
}

// ---------------------------------------------------------------------------
// Build batch permutation sorted by expert + GEMM tile table.
__global__ void route_plan(const int* __restrict__ eidx, int* __restrict__ perm,
                           int* __restrict__ tile_e, int* __restrict__ tile_row0,
                           int* __restrict__ tile_rows) {
  __shared__ int cnt[ENUM], start[ENUM];
  int t = threadIdx.x;  // 64
  if (t < ENUM) {
    int c = 0;
    for (int b = 0; b < BNUM; ++b) if (eidx[b] == t) ++c;
    cnt[t] = c;
  }
  __syncthreads();
  if (t == 0) {
    int s = 0;
    for (int e = 0; e < ENUM; ++e) { start[e] = s; s += cnt[e]; }
  }
  __syncthreads();
  if (t < ENUM) {
    int pos = start[t];
    for (int b = 0; b < BNUM; ++b) if (eidx[b] == t) perm[pos++] = b;
  }
  __syncthreads();
  if (t == 0) {
    int tile = 0;
    for (int e = 0; e < ENUM; ++e) {
      int rows = cnt[e] * HW;
      int row0 = start[e] * HW;
      int off = 0;
      while (off < rows) {
        tile_e[tile] = e;
        tile_row0[tile] = row0 + off;
        int rem = rows - off;
        tile_rows[tile] = rem < BM ? rem : BM;
        ++tile; off += BM;
      }
    }
    for (; tile < MAXTILE; ++tile) { tile_rows[tile] = 0; tile_e[tile] = 0; tile_row0[tile] = 0; }
  }
}

// ---------------------------------------------------------------------------
// LayerNorm: reads unsorted x via perm, writes sorted h as split bf16 (hi/lo).
__global__ __launch_bounds__(256) void ln_kernel(
    const float* __restrict__ xin, unsigned short* __restrict__ hhi,
    unsigned short* __restrict__ hlo,
    const float* __restrict__ g, const float* __restrict__ bta,
    const int* __restrict__ eidx, const int* __restrict__ perm, int li) {
  int t = blockIdx.x;          // sorted token id
  int s = t / HW, p = t - s * HW;
  int b = perm[s];
  int e = eidx[b];
  int c = threadIdx.x;
  float vx = xin[((size_t)b * HW + p) * CH + c];
  float sm = vx;
  for (int off = 32; off > 0; off >>= 1) sm += __shfl_down(sm, off, 64);
  __shared__ float wsum[4];
  __shared__ float red[2];
  int wid = c >> 6, lane = c & 63;
  if (lane == 0) wsum[wid] = sm;
  __syncthreads();
  if (c == 0) red[0] = (wsum[0] + wsum[1] + wsum[2] + wsum[3]) * (1.0f / (float)CH);
  __syncthreads();
  float mu = red[0];
  float d = vx - mu;
  float s2 = d * d;
  for (int off = 32; off > 0; off >>= 1) s2 += __shfl_down(s2, off, 64);
  if (lane == 0) wsum[wid] = s2;
  __syncthreads();
  if (c == 0) red[1] = (wsum[0] + wsum[1] + wsum[2] + wsum[3]) * (1.0f / (float)CH);
  __syncthreads();
  float rs = rsqrtf(red[1] + 1e-5f);
  size_t gb = ((size_t)li * ENUM + e) * CH + c;
  float hv = d * rs * g[gb] + bta[gb];
  unsigned short hi, lo;
  split_bf(hv, hi, lo);
  hhi[(size_t)t * CH + c] = hi;
  hlo[(size_t)t * CH + c] = lo;
}

// ---------------------------------------------------------------------------
// Split-bf16 MFMA grouped GEMM.
// C = A(fp32 as hi+lo bf16) @ W(fp32, split on stage) + bias
// A is sorted-token-major, stride KDIM. Tiles: BM=128 x BN_, K-step 32.
// 512 threads = 8 waves, wave grid WR x WC, wave tile (128/WR) x (BN_/WC).
// EPI: 0 = QKV (blockIdx.x selects weight 0/1/2, fp32 store)
//      1 = GELU, split-bf16 store to Omhi/Omlo (stride MLP)
//      2 = residual add into unsorted X via perm
//      3 = (acc+bias+X)*wgt -> X and O0 (out)
template <int EPI, int BN_, int KDIM, int WR, int WC>
__global__ __launch_bounds__(512) void gemm_mfma(
    const unsigned short* __restrict__ Ahi, const unsigned short* __restrict__ Alo,
    const float* __restrict__ W0, const float* __restrict__ W1p, const float* __restrict__ W2p,
    const float* __restrict__ B0, const float* __restrict__ B1p, const float* __restrict__ B2p,
    float* __restrict__ O0, float* __restrict__ O1p, float* __restrict__ O2p,
    unsigned short* __restrict__ Omhi, unsigned short* __restrict__ Omlo,
    float* __restrict__ X, const float* __restrict__ wgt,
    const int* __restrict__ tile_e, const int* __restrict__ tile_row0,
    const int* __restrict__ tile_rows, const int* __restrict__ perm, int li) {
  constexpr int FM = 128 / (WR * 16);
  constexpr int FN = BN_ / (WC * 16);
  int rows = tile_rows[blockIdx.y];
  if (rows <= 0) return;
  int row0 = tile_row0[blockIdx.y];
  int e = tile_e[blockIdx.y];
  int cb = blockIdx.x;

  const float* Wt = (EPI == 0) ? (cb == 0 ? W0 : (cb == 1 ? W1p : W2p)) : W0;
  const float* Bt = (EPI == 0) ? (cb == 0 ? B0 : (cb == 1 ? B1p : B2p)) : B0;
  float* Oo = (EPI == 0) ? (cb == 0 ? O0 : (cb == 1 ? O1p : O2p)) : O0;

  const float* Wbase = Wt + ((size_t)li * ENUM + e) * KDIM * BN_;
  const float* bias = Bt + ((size_t)li * ENUM + e) * BN_;

  __shared__ unsigned short Ash[4][BM][8];
  __shared__ unsigned short Asl[4][BM][8];
  __shared__ unsigned short Bsh[4][BN_][8];
  __shared__ unsigned short Bsl[4][BN_][8];

  int tid = threadIdx.x;
  int lane = tid & 63, wid = tid >> 6;
  int wr = wid / WC, wc = wid % WC;
  int r0w = wr * (128 / WR), c0w = wc * (BN_ / WC);
  int lrow = lane & 15, lk = lane >> 4;

  f32x4 acc[FM][FN];
#pragma unroll
  for (int i = 0; i < FM; ++i)
#pragma unroll
    for (int j = 0; j < FN; ++j) acc[i][j] = (f32x4){0.f, 0.f, 0.f, 0.f};

  // A staging map: 512 threads = 4 kgroups x 128 rows
  int skg = tid >> 7, srow = tid & 127;
  int arow = (srow < rows) ? (row0 + srow) : row0;
  const unsigned short* aph = Ahi + (size_t)arow * KDIM + skg * 8;
  const unsigned short* apl = Alo + (size_t)arow * KDIM + skg * 8;

  for (int k0 = 0; k0 < KDIM; k0 += 32) {
    // ---- stage A (pre-split bf16, direct 16B copies)
    *reinterpret_cast<uint4*>(&Ash[skg][srow][0]) =
        *reinterpret_cast<const uint4*>(aph + k0);
    *reinterpret_cast<uint4*>(&Asl[skg][srow][0]) =
        *reinterpret_cast<const uint4*>(apl + k0);
    // ---- stage B (fp32 -> split bf16, transpose-on-stage)
#pragma unroll
    for (int it = 0; it < (BN_ * 4) / 512; ++it) {
      int id = tid + it * 512;
      int n = id & (BN_ - 1);
      int kc = id / BN_;
      const float* wp = Wbase + (size_t)(k0 + kc * 8) * BN_ + n;
      unsigned short hs[8], ls[8];
#pragma unroll
      for (int j = 0; j < 8; ++j) {
        float v = wp[(size_t)j * BN_];
        split_bf(v, hs[j], ls[j]);
      }
      uint4 ph, pl;
      ph.x = hs[0] | ((unsigned)hs[1] << 16); ph.y = hs[2] | ((unsigned)hs[3] << 16);
      ph.z = hs[4] | ((unsigned)hs[5] << 16); ph.w = hs[6] | ((unsigned)hs[7] << 16);
      pl.x = ls[0] | ((unsigned)ls[1] << 16); pl.y = ls[2] | ((unsigned)ls[3] << 16);
      pl.z = ls[4] | ((unsigned)ls[5] << 16); pl.w = ls[6] | ((unsigned)ls[7] << 16);
      *reinterpret_cast<uint4*>(&Bsh[kc][n][0]) = ph;
      *reinterpret_cast<uint4*>(&Bsl[kc][n][0]) = pl;
    }
    __syncthreads();
    // ---- fragments + MFMA (3 terms: hi*hi, hi*lo, lo*hi)
    bf16x8 afh[FM], bfh[FN], bfl[FN];
#pragma unroll
    for (int fi = 0; fi < FM; ++fi)
      afh[fi] = *reinterpret_cast<const bf16x8*>(&Ash[lk][r0w + fi * 16 + lrow][0]);
#pragma unroll
    for (int fj = 0; fj < FN; ++fj) {
      bfh[fj] = *reinterpret_cast<const bf16x8*>(&Bsh[lk][c0w + fj * 16 + lrow][0]);
      bfl[fj] = *reinterpret_cast<const bf16x8*>(&Bsl[lk][c0w + fj * 16 + lrow][0]);
    }
#pragma unroll
    for (int fi = 0; fi < FM; ++fi)
#pragma unroll
      for (int fj = 0; fj < FN; ++fj) {
        acc[fi][fj] = __builtin_amdgcn_mfma_f32_16x16x32_bf16(afh[fi], bfh[fj], acc[fi][fj], 0, 0, 0);
        acc[fi][fj] = __builtin_amdgcn_mfma_f32_16x16x32_bf16(afh[fi], bfl[fj], acc[fi][fj], 0, 0, 0);
      }
    bf16x8 afl[FM];
#pragma unroll
    for (int fi = 0; fi < FM; ++fi)
      afl[fi] = *reinterpret_cast<const bf16x8*>(&Asl[lk][r0w + fi * 16 + lrow][0]);
#pragma unroll
    for (int fi = 0; fi < FM; ++fi)
#pragma unroll
      for (int fj = 0; fj < FN; ++fj)
        acc[fi][fj] = __builtin_amdgcn_mfma_f32_16x16x32_bf16(afl[fi], bfh[fj], acc[fi][fj], 0, 0, 0);
    __syncthreads();
  }

  // ---- epilogue
  float w = (EPI == 3) ? wgt[0] : 1.0f;  // placeholder; real load below per row
#pragma unroll
  for (int fi = 0; fi < FM; ++fi) {
#pragma unroll
    for (int r = 0; r < 4; ++r) {
      int row_l = r0w + fi * 16 + lk * 4 + r;
      if (row_l >= rows) continue;
      int rg = row0 + row_l;
      int bsrt = 0; size_t gxb = 0; float wr_ = 1.f;
      if (EPI >= 2) {
        int s = rg / HW, p = rg - s * HW;
        bsrt = perm[s];
        gxb = ((size_t)bsrt * HW + p) * CH;
        if (EPI == 3) wr_ = wgt[bsrt];
      }
#pragma unroll
      for (int fj = 0; fj < FN; ++fj) {
        int col = c0w + fj * 16 + lrow;
        float v = acc[fi][fj][r] + bias[col];
        if (EPI == 0) {
          Oo[(size_t)rg * BN_ + col] = v;
        } else if (EPI == 1) {
          float gl = 0.5f * v * (1.0f + erff(v * 0.70710678118654752f));
          unsigned short hi, lo;
          split_bf(gl, hi, lo);
          Omhi[(size_t)rg * MLP + col] = hi;
          Omlo[(size_t)rg * MLP + col] = lo;
        } else if (EPI == 2) {
          X[gxb + col] += v;
        } else {
          float vv = (v + X[gxb + col]) * wr_;
          X[gxb + col] = vv;
          O0[gxb + col] = vv;
        }
      }
    }
  }
  (void)w;
}

// ---------------------------------------------------------------------------
// Row-local attention on sorted fp32 q/k/v; writes split-bf16 o into h buffers.
__global__ __launch_bounds__(256) void attn_kernel(
    const float* __restrict__ q, const float* __restrict__ k,
    const float* __restrict__ v, unsigned short* __restrict__ ohi,
    unsigned short* __restrict__ olo) {
  int br = blockIdx.x;  // sorted_batch*14 + row
  int b = br / ROWLEN, row = br % ROWLEN;
  size_t base = ((size_t)b * HW + (size_t)row * ROWLEN) * CH;
  __shared__ float qs[ROWLEN][CH + 1];
  __shared__ float ks[ROWLEN][CH + 1];
  __shared__ float vs[ROWLEN][CH + 1];
  __shared__ float sc[4][ROWLEN][ROWLEN];
  int tid = threadIdx.x;  // 256
  for (int w = 0; w < ROWLEN; ++w) {
    qs[w][tid] = q[base + (size_t)w * CH + tid];
    ks[w][tid] = k[base + (size_t)w * CH + tid];
    vs[w][tid] = v[base + (size_t)w * CH + tid];
  }
  __syncthreads();
  for (int sidx = tid; sidx < 4 * ROWLEN * ROWLEN; sidx += 256) {
    int n = sidx / (ROWLEN * ROWLEN);
    int rem = sidx % (ROWLEN * ROWLEN);
    int i = rem / ROWLEN, j = rem % ROWLEN;
    const float* qp = &qs[i][n * 64];
    const float* kp = &ks[j][n * 64];
    float s = 0.f;
#pragma unroll
    for (int d = 0; d < 64; ++d) s = fmaf(qp[d], kp[d], s);
    sc[n][i][j] = s * 0.125f;
  }
  __syncthreads();
  if (tid < 4 * ROWLEN) {
    int n = tid / ROWLEN, i = tid % ROWLEN;
    float mx = sc[n][i][0];
    for (int j = 1; j < ROWLEN; ++j) mx = fmaxf(mx, sc[n][i][j]);
    float ex[ROWLEN]; float den = 0.f;
    for (int j = 0; j < ROWLEN; ++j) { ex[j] = expf(sc[n][i][j] - mx); den += ex[j]; }
    float inv = 1.0f / den;
    for (int j = 0; j < ROWLEN; ++j) sc[n][i][j] = ex[j] * inv;
  }
  __syncthreads();
  int n = tid / 64;
  for (int i = 0; i < ROWLEN; ++i) {
    float s = 0.f;
#pragma unroll
    for (int j = 0; j < ROWLEN; ++j) s = fmaf(sc[n][i][j], vs[j][tid], s);
    unsigned short hi, lo;
    split_bf(s, hi, lo);
    ohi[base + (size_t)i * CH + tid] = hi;
    olo[base + (size_t)i * CH + tid] = lo;
  }
}

// ---------------------------------------------------------------------------
extern "C" void kernel_launch(void* const* d_in, const int* in_sizes, int n_in,
                              void* d_out, int out_size, void* d_ws, size_t ws_size,
                              hipStream_t stream) {
  const float* stem = (const float*)d_in[0];
  const float* gate_w = (const float*)d_in[1];
  const float* gate_b = (const float*)d_in[2];
  const float* ln1_g = (const float*)d_in[3];
  const float* ln1_b = (const float*)d_in[4];
  const float* wq = (const float*)d_in[5];
  const float* bq = (const float*)d_in[6];
  const float* wk = (const float*)d_in[7];
  const float* bk = (const float*)d_in[8];
  const float* wv = (const float*)d_in[9];
  const float* bv = (const float*)d_in[10];
  const float* wo = (const float*)d_in[11];
  const float* bo = (const float*)d_in[12];
  const float* ln2_g = (const float*)d_in[13];
  const float* ln2_b = (const float*)d_in[14];
  const float* w1 = (const float*)d_in[15];
  const float* b1 = (const float*)d_in[16];
  const float* w2 = (const float*)d_in[17];
  const float* b2 = (const float*)d_in[18];

  float* out = (float*)d_out;
  float* ws = (float*)d_ws;
  const size_t IMG = (size_t)BNUM * HW * CH;  // 6,422,528 floats
  float* x = ws;                                       // fp32 residual
  unsigned short* h_hi = (unsigned short*)(ws + IMG);  // MTOT*CH ushorts
  unsigned short* h_lo = h_hi + (size_t)MTOT * CH;     // (together = IMG floats)
  float* q = ws + 2 * IMG;
  float* k = ws + 3 * IMG;
  float* v = ws + 4 * IMG;
  unsigned short* m_hi = (unsigned short*)q;  // alias: q dead after attn
  unsigned short* m_lo = m_hi + (size_t)MTOT * MLP;
  float* weight = ws + 5 * IMG;
  int* eidx = (int*)(weight + BNUM);
  int* perm = eidx + BNUM;
  int* tile_e = perm + BNUM;
  int* tile_row0 = tile_e + MAXTILE;
  int* tile_rows = tile_row0 + MAXTILE;

  float* probs_out = out + 4 * IMG;
  float* idx_out = probs_out + (size_t)LNUM * BNUM * ENUM;

  transpose_stem<<<dim3(8, 7, BNUM), dim3(32, 8), 0, stream>>>(stem, x);

  for (int li = 0; li < LNUM; ++li) {
    router_kernel<<<BNUM, 256, 0, stream>>>(x, gate_w, gate_b, probs_out, idx_out,
                                            weight, eidx, li);
    route_plan<<<1, 64, 0, stream>>>(eidx, perm, tile_e, tile_row0, tile_rows);
    ln_kernel<<<MTOT, 256, 0, stream>>>(x, h_hi, h_lo, ln1_g, ln1_b, eidx, perm, li);
    // QKV: 3 col-blocks (one per weight)
    gemm_mfma<0, 256, 256, 2, 4><<<dim3(3, MAXTILE), 512, 0, stream>>>(
        h_hi, h_lo, wq, wk, wv, bq, bk, bv, q, k, v, nullptr, nullptr,
        nullptr, nullptr, tile_e, tile_row0, tile_rows, perm, li);
    attn_kernel<<<BNUM * ROWLEN, 256, 0, stream>>>(q, k, v, h_hi, h_lo);
    gemm_mfma<2, 256, 256, 2, 4><<<dim3(1, MAXTILE), 512, 0, stream>>>(
        h_hi, h_lo, wo, nullptr, nullptr, bo, nullptr, nullptr, nullptr, nullptr,
        nullptr, nullptr, nullptr, x, nullptr, tile_e, tile_row0, tile_rows, perm, li);
    ln_kernel<<<MTOT, 256, 0, stream>>>(x, h_hi, h_lo, ln2_g, ln2_b, eidx, perm, li);
    gemm_mfma<1, 128, 256, 4, 2><<<dim3(1, MAXTILE), 512, 0, stream>>>(
        h_hi, h_lo, w1, nullptr, nullptr, b1, nullptr, nullptr, nullptr, nullptr,
        nullptr, m_hi, m_lo, nullptr, nullptr, tile_e, tile_row0, tile_rows, perm, li);
    gemm_mfma<3, 256, 128, 2, 4><<<dim3(1, MAXTILE), 512, 0, stream>>>(
        m_hi, m_lo, w2, nullptr, nullptr, b2, nullptr, nullptr,
        out + (size_t)li * IMG, nullptr, nullptr, nullptr, nullptr, x, weight,
        tile_e, tile_row0, tile_rows, perm, li);
  }
}